// Round 3
// baseline (1522.625 us; speedup 1.0000x reference)
//
#include <hip/hip_runtime.h>

#define NN 100000
#define NE 1600000
#define HD 128
#define EPSV 1e-8f
#define EB 128      // edges per block in k_edge
#define LPAD 136    // padded LDS row length (bf16 elems): 272 B, 16B-aligned

typedef unsigned short ushort_t;
typedef __attribute__((ext_vector_type(8))) short bf16x8;
typedef __attribute__((ext_vector_type(4))) float f32x4;

__device__ __forceinline__ float silu_f(float x) {
    return x / (1.0f + __expf(-x));
}
__device__ __forceinline__ float b2f(unsigned short u) {
    union { unsigned int i; float f; } v; v.i = ((unsigned int)u) << 16; return v.f;
}
__device__ __forceinline__ unsigned short f2b(float f) {
    union { float f; unsigned int i; } v; v.f = f;
    unsigned int r = v.i + 0x7fff + ((v.i >> 16) & 1);
    return (unsigned short)(r >> 16);
}

// ---------------------------------------------------------------------------
// Kernel 0: transpose We2, Wc1 to bf16 [n][k] layout for MFMA B-operand.
// ---------------------------------------------------------------------------
extern "C" __global__ __launch_bounds__(256)
void k_prep(const float* __restrict__ We2, const float* __restrict__ Wc1,
            ushort_t* __restrict__ We2T, ushort_t* __restrict__ Wc1T)
{
    int id = blockIdx.x * 256 + threadIdx.x;
    if (id >= 2 * HD * HD) return;
    int mat = id >> 14;
    int r = id & 16383;
    int n = r >> 7, k = r & 127;
    const float* src = mat ? Wc1 : We2;
    ushort_t* dst = mat ? Wc1T : We2T;
    dst[r] = f2b(src[k * HD + n]);
}

// ---------------------------------------------------------------------------
// Kernel 1: A[n] = h[n]@We1[0:128,:]+be1 ; B[n] = h[n]@We1[128:256,:]  (bf16 out)
// ---------------------------------------------------------------------------
extern "C" __global__ __launch_bounds__(256)
void k_nodeAB(const float* __restrict__ h, const float* __restrict__ We1,
              const float* __restrict__ be1, ushort_t* __restrict__ A,
              ushort_t* __restrict__ B)
{
    __shared__ float hs[16][HD];
    const int tid = threadIdx.x;
    const int j = tid & 127;
    const int mat = tid >> 7;
    const int n0 = blockIdx.x * 16;
    for (int i = tid; i < 16 * HD; i += 256) {
        hs[i >> 7][i & 127] = h[(size_t)(n0 + (i >> 7)) * HD + (i & 127)];
    }
    __syncthreads();
    float acc[16];
#pragma unroll
    for (int ni = 0; ni < 16; ni++) acc[ni] = 0.f;
    const float* W = We1 + (size_t)mat * HD * HD + j;
    for (int k4 = 0; k4 < 32; k4++) {
        float w0 = W[(size_t)(4 * k4 + 0) * HD];
        float w1 = W[(size_t)(4 * k4 + 1) * HD];
        float w2 = W[(size_t)(4 * k4 + 2) * HD];
        float w3 = W[(size_t)(4 * k4 + 3) * HD];
#pragma unroll
        for (int ni = 0; ni < 16; ni++) {
            float4 hv = *(const float4*)&hs[ni][4 * k4];
            acc[ni] += hv.x * w0 + hv.y * w1 + hv.z * w2 + hv.w * w3;
        }
    }
    float bias = (mat == 0) ? be1[j] : 0.f;
    ushort_t* dst = (mat == 0) ? A : B;
#pragma unroll
    for (int ni = 0; ni < 16; ni++) {
        dst[(size_t)(n0 + ni) * HD + j] = f2b(acc[ni] + bias);
    }
}

// ---------------------------------------------------------------------------
// Kernel 2: MFMA edge kernel. 128 edges / 256 threads / 4 waves per block.
// All phases wave-local (wave w owns edge rows [32w,32w+32)) except the
// final transposed agg_h scatter -> exactly one __syncthreads().
// Weights (We2T/Wc1T) read directly from global (L1/L2-hot, 32KB each).
// ---------------------------------------------------------------------------
extern "C" __global__ __launch_bounds__(256, 4)
void k_edge(const int* __restrict__ ei, const float* __restrict__ coord,
            const ushort_t* __restrict__ A, const ushort_t* __restrict__ B,
            const float* __restrict__ WeL, const float* __restrict__ be2,
            const ushort_t* __restrict__ We2T,
            const ushort_t* __restrict__ Wc1T,
            const float* __restrict__ bc1, const float* __restrict__ Wc2,
            float* __restrict__ agg_h, float* __restrict__ agg_c,
            float* __restrict__ cnt)
{
    __shared__ ushort_t m_lds[EB][LPAD] __attribute__((aligned(16)));
    __shared__ float cd_lds[EB][4];
    __shared__ int rows_s[EB];

    const int tid = threadIdx.x;
    const int e  = tid >> 1;       // edge slot 0..127
    const int hf = tid & 1;        // feature half
    const int ge = blockIdx.x * EB + e;
    const int row = ei[ge];
    const int col = ei[NE + ge];

    // ---- phase 0: coord/radial, m1 -> LDS (wave-local rows) ----
    float c0 = coord[(size_t)row * 3 + 0] - coord[(size_t)col * 3 + 0];
    float c1 = coord[(size_t)row * 3 + 1] - coord[(size_t)col * 3 + 1];
    float c2 = coord[(size_t)row * 3 + 2] - coord[(size_t)col * 3 + 2];
    float radial = c0 * c0 + c1 * c1 + c2 * c2;
    if (hf == 0) {
        rows_s[e] = row;
        float inv = 1.0f / (sqrtf(radial) + EPSV);
        cd_lds[e][0] = c0 * inv; cd_lds[e][1] = c1 * inv; cd_lds[e][2] = c2 * inv;
    }

    {
        const bf16x8* A8 = (const bf16x8*)(A + (size_t)row * HD + hf * 64);
        const bf16x8* B8 = (const bf16x8*)(B + (size_t)col * HD + hf * 64);
        const float4* WL4 = (const float4*)WeL + hf * 16;
#pragma unroll
        for (int i = 0; i < 8; i++) {
            bf16x8 av = A8[i], bv = B8[i];
            float4 w0 = WL4[2 * i], w1 = WL4[2 * i + 1];
            bf16x8 pk;
            pk[0] = (short)f2b(silu_f(b2f((ushort_t)av[0]) + b2f((ushort_t)bv[0]) + radial * w0.x));
            pk[1] = (short)f2b(silu_f(b2f((ushort_t)av[1]) + b2f((ushort_t)bv[1]) + radial * w0.y));
            pk[2] = (short)f2b(silu_f(b2f((ushort_t)av[2]) + b2f((ushort_t)bv[2]) + radial * w0.z));
            pk[3] = (short)f2b(silu_f(b2f((ushort_t)av[3]) + b2f((ushort_t)bv[3]) + radial * w0.w));
            pk[4] = (short)f2b(silu_f(b2f((ushort_t)av[4]) + b2f((ushort_t)bv[4]) + radial * w1.x));
            pk[5] = (short)f2b(silu_f(b2f((ushort_t)av[5]) + b2f((ushort_t)bv[5]) + radial * w1.y));
            pk[6] = (short)f2b(silu_f(b2f((ushort_t)av[6]) + b2f((ushort_t)bv[6]) + radial * w1.z));
            pk[7] = (short)f2b(silu_f(b2f((ushort_t)av[7]) + b2f((ushort_t)bv[7]) + radial * w1.w));
            *(bf16x8*)&m_lds[e][hf * 64 + i * 8] = pk;
        }
    }
    // no barrier: wave w wrote rows [32w,32w+32) and only reads those below

    const int wave = tid >> 6, lane = tid & 63;
    const int lr = lane & 15, lg = lane >> 4;

    // ---- GEMM1: m1 @ We2 ----
    f32x4 acc[2][8];
#pragma unroll
    for (int mt = 0; mt < 2; mt++)
#pragma unroll
        for (int nt = 0; nt < 8; nt++) acc[mt][nt] = (f32x4){0.f, 0.f, 0.f, 0.f};

#pragma unroll
    for (int ks = 0; ks < 4; ks++) {
        bf16x8 af0 = *(const bf16x8*)&m_lds[wave * 32 + lr][ks * 32 + lg * 8];
        bf16x8 af1 = *(const bf16x8*)&m_lds[wave * 32 + 16 + lr][ks * 32 + lg * 8];
#pragma unroll
        for (int nt = 0; nt < 8; nt++) {
            bf16x8 bf = *(const bf16x8*)(We2T + (size_t)(nt * 16 + lr) * HD + ks * 32 + lg * 8);
            acc[0][nt] = __builtin_amdgcn_mfma_f32_16x16x32_bf16(af0, bf, acc[0][nt], 0, 0, 0);
            acc[1][nt] = __builtin_amdgcn_mfma_f32_16x16x32_bf16(af1, bf, acc[1][nt], 0, 0, 0);
        }
    }

    // m = silu(acc + be2) -> back into m_lds (own wave's 32 rows only)
#pragma unroll
    for (int nt = 0; nt < 8; nt++) {
        float be2v = be2[nt * 16 + lr];
#pragma unroll
        for (int mt = 0; mt < 2; mt++)
#pragma unroll
            for (int r = 0; r < 4; r++) {
                int rrow = wave * 32 + mt * 16 + lg * 4 + r;
                m_lds[rrow][nt * 16 + lr] = f2b(silu_f(acc[mt][nt][r] + be2v));
            }
    }
    // no barrier: GEMM2 A-frags read own wave's rows only

    // ---- GEMM2: m @ Wc1 ----
#pragma unroll
    for (int mt = 0; mt < 2; mt++)
#pragma unroll
        for (int nt = 0; nt < 8; nt++) acc[mt][nt] = (f32x4){0.f, 0.f, 0.f, 0.f};

#pragma unroll
    for (int ks = 0; ks < 4; ks++) {
        bf16x8 af0 = *(const bf16x8*)&m_lds[wave * 32 + lr][ks * 32 + lg * 8];
        bf16x8 af1 = *(const bf16x8*)&m_lds[wave * 32 + 16 + lr][ks * 32 + lg * 8];
#pragma unroll
        for (int nt = 0; nt < 8; nt++) {
            bf16x8 bf = *(const bf16x8*)(Wc1T + (size_t)(nt * 16 + lr) * HD + ks * 32 + lg * 8);
            acc[0][nt] = __builtin_amdgcn_mfma_f32_16x16x32_bf16(af0, bf, acc[0][nt], 0, 0, 0);
            acc[1][nt] = __builtin_amdgcn_mfma_f32_16x16x32_bf16(af1, bf, acc[1][nt], 0, 0, 0);
        }
    }

    // phi = sum_j silu(u + bc1) * Wc2, reduced across the 16 col-lanes
    float ph[2][4];
#pragma unroll
    for (int mt = 0; mt < 2; mt++)
#pragma unroll
        for (int r = 0; r < 4; r++) ph[mt][r] = 0.f;
#pragma unroll
    for (int nt = 0; nt < 8; nt++) {
        float bc1v = bc1[nt * 16 + lr];
        float wc2v = Wc2[nt * 16 + lr];
#pragma unroll
        for (int mt = 0; mt < 2; mt++)
#pragma unroll
            for (int r = 0; r < 4; r++)
                ph[mt][r] += silu_f(acc[mt][nt][r] + bc1v) * wc2v;
    }
#pragma unroll
    for (int msk = 1; msk < 16; msk <<= 1)
#pragma unroll
        for (int mt = 0; mt < 2; mt++)
#pragma unroll
            for (int r = 0; r < 4; r++)
                ph[mt][r] += __shfl_xor(ph[mt][r], msk, 64);

    if (lr == 0) {
#pragma unroll
        for (int mt = 0; mt < 2; mt++)
#pragma unroll
            for (int r = 0; r < 4; r++) {
                int er = wave * 32 + mt * 16 + lg * 4 + r;
                int ro = rows_s[er];
                float p = ph[mt][r];
                atomicAdd(&agg_c[(size_t)ro * 3 + 0], cd_lds[er][0] * p);
                atomicAdd(&agg_c[(size_t)ro * 3 + 1], cd_lds[er][1] * p);
                atomicAdd(&agg_c[(size_t)ro * 3 + 2], cd_lds[er][2] * p);
                atomicAdd(&cnt[ro], 1.0f);
            }
    }

    __syncthreads();   // the only barrier: scatter reads all waves' m rows

    // ---- agg_h scatter: coalesced, 128 lanes cover one edge row ----
    {
        const int j = tid & 127, g = tid >> 7;
        for (int eb = 0; eb < 64; eb++) {
            int es = eb * 2 + g;
            atomicAdd(&agg_h[(size_t)rows_s[es] * HD + j], b2f(m_lds[es][j]));
        }
    }
}

// ---------------------------------------------------------------------------
// Kernel 3: node MLP, one node per thread, j chunked 2x64 (no spills).
// ---------------------------------------------------------------------------
extern "C" __global__ __launch_bounds__(256)
void k_node(const float* __restrict__ h, const float* __restrict__ Wn1,
            const float* __restrict__ bn1, const float* __restrict__ Wn2,
            const float* __restrict__ bn2, const float* __restrict__ coord,
            const float* __restrict__ cnt,
            float* __restrict__ hout /* = agg_h in */,
            float* __restrict__ cout /* = agg_c in */)
{
    __shared__ unsigned short u_lds[HD][257];
    const int tid = threadIdx.x;
    const int n = blockIdx.x * 256 + tid;
    if (n >= NN) return;  // no barriers below -> safe

    const float4* H4 = (const float4*)(h + (size_t)n * HD);
    const float4* G4 = (const float4*)(hout + (size_t)n * HD);

    for (int half = 0; half < 2; half++) {
        float acc[64];
#pragma unroll
        for (int j = 0; j < 64; j++) acc[j] = bn1[half * 64 + j];
        for (int k4 = 0; k4 < 32; k4++) {
            float4 hv = H4[k4];
            const float* w0 = Wn1 + (size_t)(4 * k4 + 0) * HD + half * 64;
            const float* w1 = Wn1 + (size_t)(4 * k4 + 1) * HD + half * 64;
            const float* w2 = Wn1 + (size_t)(4 * k4 + 2) * HD + half * 64;
            const float* w3 = Wn1 + (size_t)(4 * k4 + 3) * HD + half * 64;
#pragma unroll
            for (int j = 0; j < 64; j++)
                acc[j] += hv.x * w0[j] + hv.y * w1[j] + hv.z * w2[j] + hv.w * w3[j];
        }
        for (int k4 = 0; k4 < 32; k4++) {
            float4 gv = G4[k4];
            const float* w0 = Wn1 + (size_t)(HD + 4 * k4 + 0) * HD + half * 64;
            const float* w1 = Wn1 + (size_t)(HD + 4 * k4 + 1) * HD + half * 64;
            const float* w2 = Wn1 + (size_t)(HD + 4 * k4 + 2) * HD + half * 64;
            const float* w3 = Wn1 + (size_t)(HD + 4 * k4 + 3) * HD + half * 64;
#pragma unroll
            for (int j = 0; j < 64; j++)
                acc[j] += gv.x * w0[j] + gv.y * w1[j] + gv.z * w2[j] + gv.w * w3[j];
        }
#pragma unroll
        for (int j = 0; j < 64; j++)
            u_lds[half * 64 + j][tid] = f2b(silu_f(acc[j]));
    }

    for (int jc = 0; jc < 4; jc++) {
        float o[32];
#pragma unroll
        for (int jj = 0; jj < 32; jj++) o[jj] = bn2[jc * 32 + jj];
        for (int k = 0; k < HD; k++) {
            float uk = b2f(u_lds[k][tid]);
            const float* wr = Wn2 + (size_t)k * HD + jc * 32;
#pragma unroll
            for (int jj = 0; jj < 32; jj++) o[jj] += uk * wr[jj];
        }
#pragma unroll
        for (int jj = 0; jj < 32; jj++) {
            size_t idx = (size_t)n * HD + jc * 32 + jj;
            hout[idx] = h[idx] + o[jj];
        }
    }

    float invc = 1.0f / fmaxf(cnt[n], 1.0f);
#pragma unroll
    for (int i = 0; i < 3; i++) {
        size_t idx = (size_t)n * 3 + i;
        cout[idx] = coord[idx] + cout[idx] * invc;
    }
}

// ---------------------------------------------------------------------------
extern "C" void kernel_launch(void* const* d_in, const int* in_sizes, int n_in,
                              void* d_out, int out_size, void* d_ws, size_t ws_size,
                              hipStream_t stream)
{
    const float* h     = (const float*)d_in[0];
    const int*   ei    = (const int*)d_in[1];
    const float* coord = (const float*)d_in[2];
    const float* We1   = (const float*)d_in[3];
    const float* be1   = (const float*)d_in[4];
    const float* We2   = (const float*)d_in[5];
    const float* be2   = (const float*)d_in[6];
    const float* Wn1   = (const float*)d_in[7];
    const float* bn1   = (const float*)d_in[8];
    const float* Wn2   = (const float*)d_in[9];
    const float* bn2   = (const float*)d_in[10];
    const float* Wc1   = (const float*)d_in[11];
    const float* bc1   = (const float*)d_in[12];
    const float* Wc2   = (const float*)d_in[13];

    float* out   = (float*)d_out;
    float* agg_h = out;                         // [NN,128] accum, then h_out
    float* agg_c = out + (size_t)NN * HD;       // [NN,3]  accum, then coord_out

    ushort_t* A   = (ushort_t*)d_ws;            // [NN,128] bf16
    ushort_t* B   = A + (size_t)NN * HD;        // [NN,128] bf16
    float*   cnt  = (float*)(B + (size_t)NN * HD);       // [NN] fp32
    ushort_t* We2T = (ushort_t*)(cnt + NN);     // [128,128] bf16
    ushort_t* Wc1T = We2T + HD * HD;            // [128,128] bf16
    const float* WeL = We1 + (size_t)2 * HD * HD;  // last row of We1

    hipMemsetAsync(d_out, 0, (size_t)out_size * sizeof(float), stream);
    hipMemsetAsync(cnt, 0, (size_t)NN * sizeof(float), stream);

    k_prep<<<(2 * HD * HD + 255) / 256, 256, 0, stream>>>(We2, Wc1, We2T, Wc1T);
    k_nodeAB<<<NN / 16, 256, 0, stream>>>(h, We1, be1, A, B);
    k_edge<<<NE / EB, 256, 0, stream>>>(ei, coord, A, B, WeL, be2,
                                        We2T, Wc1T, bc1, Wc2, agg_h, agg_c, cnt);
    k_node<<<(NN + 255) / 256, 256, 0, stream>>>(h, Wn1, bn1, Wn2, bn2, coord,
                                                 cnt, agg_h, agg_c);
}

// Round 4
// 1303.945 us; speedup vs baseline: 1.1677x; 1.1677x over previous
//
#include <hip/hip_runtime.h>

#define NN 100000
#define NE 1600000
#define HD 128
#define EPSV 1e-8f
#define EB 128      // edges per block in k_edge
#define LPAD 136    // padded LDS row length (bf16 elems): 272 B, 16B-aligned

typedef unsigned short ushort_t;
typedef __attribute__((ext_vector_type(8))) short bf16x8;
typedef __attribute__((ext_vector_type(4))) float f32x4;

__device__ __forceinline__ float silu_f(float x) {
    return x / (1.0f + __expf(-x));
}
__device__ __forceinline__ float b2f(unsigned short u) {
    union { unsigned int i; float f; } v; v.i = ((unsigned int)u) << 16; return v.f;
}
__device__ __forceinline__ unsigned short f2b(float f) {
    union { float f; unsigned int i; } v; v.f = f;
    unsigned int r = v.i + 0x7fff + ((v.i >> 16) & 1);
    return (unsigned short)(r >> 16);
}

// ---------------------------------------------------------------------------
// Kernel 0: transpose We2, Wc1 to bf16 [n][k] layout for MFMA B-operand.
// ---------------------------------------------------------------------------
extern "C" __global__ __launch_bounds__(256)
void k_prep(const float* __restrict__ We2, const float* __restrict__ Wc1,
            ushort_t* __restrict__ We2T, ushort_t* __restrict__ Wc1T)
{
    int id = blockIdx.x * 256 + threadIdx.x;
    if (id >= 2 * HD * HD) return;
    int mat = id >> 14;
    int r = id & 16383;
    int n = r >> 7, k = r & 127;
    const float* src = mat ? Wc1 : We2;
    ushort_t* dst = mat ? Wc1T : We2T;
    dst[r] = f2b(src[k * HD + n]);
}

// ---------------------------------------------------------------------------
// Counting sort of edges by row: histogram -> single-block scan -> scatter ids
// ---------------------------------------------------------------------------
extern "C" __global__ __launch_bounds__(256)
void k_hist(const int* __restrict__ ei, int* __restrict__ deg)
{
    int e = blockIdx.x * 256 + threadIdx.x;
    atomicAdd(&deg[ei[e]], 1);
}

extern "C" __global__ __launch_bounds__(1024)
void k_scan(const int* __restrict__ deg, int* __restrict__ start,
            int* __restrict__ cursor)
{
    __shared__ int wsum[16];
    __shared__ int carry_s;
    const int tid = threadIdx.x;
    const int lane = tid & 63, w = tid >> 6;
    if (tid == 0) carry_s = 0;
    __syncthreads();
    for (int base = 0; base < NN; base += 1024) {
        int i = base + tid;
        int v = (i < NN) ? deg[i] : 0;
        int s = v;
#pragma unroll
        for (int off = 1; off < 64; off <<= 1) {
            int t = __shfl_up(s, off, 64);
            if (lane >= off) s += t;
        }
        if (lane == 63) wsum[w] = s;
        __syncthreads();
        int carry = carry_s;
        if (w == 0) {
            int ws = (lane < 16) ? wsum[lane] : 0;
#pragma unroll
            for (int off = 1; off < 16; off <<= 1) {
                int t = __shfl_up(ws, off, 64);
                if (lane >= off) ws += t;
            }
            if (lane < 16) wsum[lane] = ws;
        }
        __syncthreads();
        int woff = (w == 0) ? 0 : wsum[w - 1];
        int excl = carry + woff + s - v;
        if (i < NN) { start[i] = excl; cursor[i] = excl; }
        __syncthreads();
        if (tid == 0) carry_s = carry + wsum[15];
        __syncthreads();
    }
}

extern "C" __global__ __launch_bounds__(256)
void k_sortids(const int* __restrict__ ei, int* __restrict__ cursor,
               int* __restrict__ perm)
{
    int e = blockIdx.x * 256 + threadIdx.x;
    int slot = atomicAdd(&cursor[ei[e]], 1);
    perm[slot] = e;
}

// ---------------------------------------------------------------------------
// Kernel 1: A[n] = h[n]@We1[0:128,:]+be1 ; B[n] = h[n]@We1[128:256,:]  (bf16 out)
// ---------------------------------------------------------------------------
extern "C" __global__ __launch_bounds__(256)
void k_nodeAB(const float* __restrict__ h, const float* __restrict__ We1,
              const float* __restrict__ be1, ushort_t* __restrict__ A,
              ushort_t* __restrict__ B)
{
    __shared__ float hs[16][HD];
    const int tid = threadIdx.x;
    const int j = tid & 127;
    const int mat = tid >> 7;
    const int n0 = blockIdx.x * 16;
    for (int i = tid; i < 16 * HD; i += 256) {
        hs[i >> 7][i & 127] = h[(size_t)(n0 + (i >> 7)) * HD + (i & 127)];
    }
    __syncthreads();
    float acc[16];
#pragma unroll
    for (int ni = 0; ni < 16; ni++) acc[ni] = 0.f;
    const float* W = We1 + (size_t)mat * HD * HD + j;
    for (int k4 = 0; k4 < 32; k4++) {
        float w0 = W[(size_t)(4 * k4 + 0) * HD];
        float w1 = W[(size_t)(4 * k4 + 1) * HD];
        float w2 = W[(size_t)(4 * k4 + 2) * HD];
        float w3 = W[(size_t)(4 * k4 + 3) * HD];
#pragma unroll
        for (int ni = 0; ni < 16; ni++) {
            float4 hv = *(const float4*)&hs[ni][4 * k4];
            acc[ni] += hv.x * w0 + hv.y * w1 + hv.z * w2 + hv.w * w3;
        }
    }
    float bias = (mat == 0) ? be1[j] : 0.f;
    ushort_t* dst = (mat == 0) ? A : B;
#pragma unroll
    for (int ni = 0; ni < 16; ni++) {
        dst[(size_t)(n0 + ni) * HD + j] = f2b(acc[ni] + bias);
    }
}

// ---------------------------------------------------------------------------
// Kernel 2: MFMA edge kernel over SORTED edges (perm). Scatter merges
// equal-row runs in registers -> ~deg/1 fewer atomics.
// ---------------------------------------------------------------------------
extern "C" __global__ __launch_bounds__(256, 4)
void k_edge(const int* __restrict__ ei, const int* __restrict__ perm,
            const float* __restrict__ coord,
            const ushort_t* __restrict__ A, const ushort_t* __restrict__ B,
            const float* __restrict__ WeL, const float* __restrict__ be2,
            const ushort_t* __restrict__ We2T,
            const ushort_t* __restrict__ Wc1T,
            const float* __restrict__ bc1, const float* __restrict__ Wc2,
            float* __restrict__ agg_h, float* __restrict__ agg_c)
{
    __shared__ ushort_t m_lds[EB][LPAD] __attribute__((aligned(16)));
    __shared__ float cd_lds[EB][4];
    __shared__ int rows_s[EB];

    const int tid = threadIdx.x;
    const int e  = tid >> 1;       // edge slot 0..127 (sorted order)
    const int hf = tid & 1;        // feature half
    const int ge = perm[blockIdx.x * EB + e];
    const int row = ei[ge];
    const int col = ei[NE + ge];

    // ---- phase 0: coord/radial, m1 -> LDS (wave-local rows) ----
    float c0 = coord[(size_t)row * 3 + 0] - coord[(size_t)col * 3 + 0];
    float c1 = coord[(size_t)row * 3 + 1] - coord[(size_t)col * 3 + 1];
    float c2 = coord[(size_t)row * 3 + 2] - coord[(size_t)col * 3 + 2];
    float radial = c0 * c0 + c1 * c1 + c2 * c2;
    if (hf == 0) {
        rows_s[e] = row;
        float inv = 1.0f / (sqrtf(radial) + EPSV);
        cd_lds[e][0] = c0 * inv; cd_lds[e][1] = c1 * inv; cd_lds[e][2] = c2 * inv;
    }

    {
        const bf16x8* A8 = (const bf16x8*)(A + (size_t)row * HD + hf * 64);
        const bf16x8* B8 = (const bf16x8*)(B + (size_t)col * HD + hf * 64);
        const float4* WL4 = (const float4*)WeL + hf * 16;
#pragma unroll
        for (int i = 0; i < 8; i++) {
            bf16x8 av = A8[i], bv = B8[i];
            float4 w0 = WL4[2 * i], w1 = WL4[2 * i + 1];
            bf16x8 pk;
            pk[0] = (short)f2b(silu_f(b2f((ushort_t)av[0]) + b2f((ushort_t)bv[0]) + radial * w0.x));
            pk[1] = (short)f2b(silu_f(b2f((ushort_t)av[1]) + b2f((ushort_t)bv[1]) + radial * w0.y));
            pk[2] = (short)f2b(silu_f(b2f((ushort_t)av[2]) + b2f((ushort_t)bv[2]) + radial * w0.z));
            pk[3] = (short)f2b(silu_f(b2f((ushort_t)av[3]) + b2f((ushort_t)bv[3]) + radial * w0.w));
            pk[4] = (short)f2b(silu_f(b2f((ushort_t)av[4]) + b2f((ushort_t)bv[4]) + radial * w1.x));
            pk[5] = (short)f2b(silu_f(b2f((ushort_t)av[5]) + b2f((ushort_t)bv[5]) + radial * w1.y));
            pk[6] = (short)f2b(silu_f(b2f((ushort_t)av[6]) + b2f((ushort_t)bv[6]) + radial * w1.z));
            pk[7] = (short)f2b(silu_f(b2f((ushort_t)av[7]) + b2f((ushort_t)bv[7]) + radial * w1.w));
            *(bf16x8*)&m_lds[e][hf * 64 + i * 8] = pk;
        }
    }
    // no barrier: wave w wrote rows [32w,32w+32) and only reads those below

    const int wave = tid >> 6, lane = tid & 63;
    const int lr = lane & 15, lg = lane >> 4;

    // ---- GEMM1: m1 @ We2 ----
    f32x4 acc[2][8];
#pragma unroll
    for (int mt = 0; mt < 2; mt++)
#pragma unroll
        for (int nt = 0; nt < 8; nt++) acc[mt][nt] = (f32x4){0.f, 0.f, 0.f, 0.f};

#pragma unroll
    for (int ks = 0; ks < 4; ks++) {
        bf16x8 af0 = *(const bf16x8*)&m_lds[wave * 32 + lr][ks * 32 + lg * 8];
        bf16x8 af1 = *(const bf16x8*)&m_lds[wave * 32 + 16 + lr][ks * 32 + lg * 8];
#pragma unroll
        for (int nt = 0; nt < 8; nt++) {
            bf16x8 bf = *(const bf16x8*)(We2T + (size_t)(nt * 16 + lr) * HD + ks * 32 + lg * 8);
            acc[0][nt] = __builtin_amdgcn_mfma_f32_16x16x32_bf16(af0, bf, acc[0][nt], 0, 0, 0);
            acc[1][nt] = __builtin_amdgcn_mfma_f32_16x16x32_bf16(af1, bf, acc[1][nt], 0, 0, 0);
        }
    }

    // m = silu(acc + be2) -> back into m_lds (own wave's 32 rows only)
#pragma unroll
    for (int nt = 0; nt < 8; nt++) {
        float be2v = be2[nt * 16 + lr];
#pragma unroll
        for (int mt = 0; mt < 2; mt++)
#pragma unroll
            for (int r = 0; r < 4; r++) {
                int rrow = wave * 32 + mt * 16 + lg * 4 + r;
                m_lds[rrow][nt * 16 + lr] = f2b(silu_f(acc[mt][nt][r] + be2v));
            }
    }
    // no barrier: GEMM2 A-frags read own wave's rows only

    // ---- GEMM2: m @ Wc1 ----
#pragma unroll
    for (int mt = 0; mt < 2; mt++)
#pragma unroll
        for (int nt = 0; nt < 8; nt++) acc[mt][nt] = (f32x4){0.f, 0.f, 0.f, 0.f};

#pragma unroll
    for (int ks = 0; ks < 4; ks++) {
        bf16x8 af0 = *(const bf16x8*)&m_lds[wave * 32 + lr][ks * 32 + lg * 8];
        bf16x8 af1 = *(const bf16x8*)&m_lds[wave * 32 + 16 + lr][ks * 32 + lg * 8];
#pragma unroll
        for (int nt = 0; nt < 8; nt++) {
            bf16x8 bf = *(const bf16x8*)(Wc1T + (size_t)(nt * 16 + lr) * HD + ks * 32 + lg * 8);
            acc[0][nt] = __builtin_amdgcn_mfma_f32_16x16x32_bf16(af0, bf, acc[0][nt], 0, 0, 0);
            acc[1][nt] = __builtin_amdgcn_mfma_f32_16x16x32_bf16(af1, bf, acc[1][nt], 0, 0, 0);
        }
    }

    // phi = sum_j silu(u + bc1) * Wc2, reduced across the 16 col-lanes
    float ph[2][4];
#pragma unroll
    for (int mt = 0; mt < 2; mt++)
#pragma unroll
        for (int r = 0; r < 4; r++) ph[mt][r] = 0.f;
#pragma unroll
    for (int nt = 0; nt < 8; nt++) {
        float bc1v = bc1[nt * 16 + lr];
        float wc2v = Wc2[nt * 16 + lr];
#pragma unroll
        for (int mt = 0; mt < 2; mt++)
#pragma unroll
            for (int r = 0; r < 4; r++)
                ph[mt][r] += silu_f(acc[mt][nt][r] + bc1v) * wc2v;
    }
#pragma unroll
    for (int msk = 1; msk < 16; msk <<= 1)
#pragma unroll
        for (int mt = 0; mt < 2; mt++)
#pragma unroll
            for (int r = 0; r < 4; r++)
                ph[mt][r] += __shfl_xor(ph[mt][r], msk, 64);

    // scale normalized coord-diff by phi, in place (same-wave rows: er in
    // [wave*32, wave*32+32) and phase-0 writer tid=2*er is in this wave)
    if (lr == 0) {
#pragma unroll
        for (int mt = 0; mt < 2; mt++)
#pragma unroll
            for (int r = 0; r < 4; r++) {
                int er = wave * 32 + mt * 16 + lg * 4 + r;
                float p = ph[mt][r];
                cd_lds[er][0] *= p; cd_lds[er][1] *= p; cd_lds[er][2] *= p;
            }
    }

    __syncthreads();   // the only barrier: walks read all waves' rows

    // ---- agg_h: run-merged scatter. rows_s is sorted; accumulate equal-row
    // runs in a register, one atomic per run. Branches are wave-uniform.
    {
        const int j = tid & 127, g = tid >> 7;
        const int es0 = g * 64, es1 = es0 + 64;
        float acc_r = 0.f;
        int cur = rows_s[es0];
        for (int es = es0; es < es1; es++) {
            int r = rows_s[es];
            if (r != cur) {
                atomicAdd(&agg_h[(size_t)cur * HD + j], acc_r);
                acc_r = 0.f; cur = r;
            }
            acc_r += b2f(m_lds[es][j]);
        }
        atomicAdd(&agg_h[(size_t)cur * HD + j], acc_r);
    }

    // ---- agg_c: same run-merge, wave 0 only (3 comps x 16 es-segments) ----
    if (wave == 0) {
        int c = lane >> 4;        // 0..3
        int sub = lane & 15;      // 0..15
        if (c < 3) {
            const int es0 = sub * 8, es1 = es0 + 8;
            float acc_r = 0.f;
            int cur = rows_s[es0];
            for (int es = es0; es < es1; es++) {
                int r = rows_s[es];
                if (r != cur) {
                    atomicAdd(&agg_c[(size_t)cur * 3 + c], acc_r);
                    acc_r = 0.f; cur = r;
                }
                acc_r += cd_lds[es][c];
            }
            atomicAdd(&agg_c[(size_t)cur * 3 + c], acc_r);
        }
    }
}

// ---------------------------------------------------------------------------
// Kernel 3: node MLP, one node per thread, j chunked 2x64 (no spills).
// ---------------------------------------------------------------------------
extern "C" __global__ __launch_bounds__(256)
void k_node(const float* __restrict__ h, const float* __restrict__ Wn1,
            const float* __restrict__ bn1, const float* __restrict__ Wn2,
            const float* __restrict__ bn2, const float* __restrict__ coord,
            const int* __restrict__ deg,
            float* __restrict__ hout /* = agg_h in */,
            float* __restrict__ cout /* = agg_c in */)
{
    __shared__ unsigned short u_lds[HD][257];
    const int tid = threadIdx.x;
    const int n = blockIdx.x * 256 + tid;
    if (n >= NN) return;  // no barriers below -> safe

    const float4* H4 = (const float4*)(h + (size_t)n * HD);
    const float4* G4 = (const float4*)(hout + (size_t)n * HD);

    for (int half = 0; half < 2; half++) {
        float acc[64];
#pragma unroll
        for (int j = 0; j < 64; j++) acc[j] = bn1[half * 64 + j];
        for (int k4 = 0; k4 < 32; k4++) {
            float4 hv = H4[k4];
            const float* w0 = Wn1 + (size_t)(4 * k4 + 0) * HD + half * 64;
            const float* w1 = Wn1 + (size_t)(4 * k4 + 1) * HD + half * 64;
            const float* w2 = Wn1 + (size_t)(4 * k4 + 2) * HD + half * 64;
            const float* w3 = Wn1 + (size_t)(4 * k4 + 3) * HD + half * 64;
#pragma unroll
            for (int j = 0; j < 64; j++)
                acc[j] += hv.x * w0[j] + hv.y * w1[j] + hv.z * w2[j] + hv.w * w3[j];
        }
        for (int k4 = 0; k4 < 32; k4++) {
            float4 gv = G4[k4];
            const float* w0 = Wn1 + (size_t)(HD + 4 * k4 + 0) * HD + half * 64;
            const float* w1 = Wn1 + (size_t)(HD + 4 * k4 + 1) * HD + half * 64;
            const float* w2 = Wn1 + (size_t)(HD + 4 * k4 + 2) * HD + half * 64;
            const float* w3 = Wn1 + (size_t)(HD + 4 * k4 + 3) * HD + half * 64;
#pragma unroll
            for (int j = 0; j < 64; j++)
                acc[j] += gv.x * w0[j] + gv.y * w1[j] + gv.z * w2[j] + gv.w * w3[j];
        }
#pragma unroll
        for (int j = 0; j < 64; j++)
            u_lds[half * 64 + j][tid] = f2b(silu_f(acc[j]));
    }

    for (int jc = 0; jc < 4; jc++) {
        float o[32];
#pragma unroll
        for (int jj = 0; jj < 32; jj++) o[jj] = bn2[jc * 32 + jj];
        for (int k = 0; k < HD; k++) {
            float uk = b2f(u_lds[k][tid]);
            const float* wr = Wn2 + (size_t)k * HD + jc * 32;
#pragma unroll
            for (int jj = 0; jj < 32; jj++) o[jj] += uk * wr[jj];
        }
#pragma unroll
        for (int jj = 0; jj < 32; jj++) {
            size_t idx = (size_t)n * HD + jc * 32 + jj;
            hout[idx] = h[idx] + o[jj];
        }
    }

    float invc = 1.0f / fmaxf((float)deg[n], 1.0f);
#pragma unroll
    for (int i = 0; i < 3; i++) {
        size_t idx = (size_t)n * 3 + i;
        cout[idx] = coord[idx] + cout[idx] * invc;
    }
}

// ---------------------------------------------------------------------------
extern "C" void kernel_launch(void* const* d_in, const int* in_sizes, int n_in,
                              void* d_out, int out_size, void* d_ws, size_t ws_size,
                              hipStream_t stream)
{
    const float* h     = (const float*)d_in[0];
    const int*   ei    = (const int*)d_in[1];
    const float* coord = (const float*)d_in[2];
    const float* We1   = (const float*)d_in[3];
    const float* be1   = (const float*)d_in[4];
    const float* We2   = (const float*)d_in[5];
    const float* be2   = (const float*)d_in[6];
    const float* Wn1   = (const float*)d_in[7];
    const float* bn1   = (const float*)d_in[8];
    const float* Wn2   = (const float*)d_in[9];
    const float* bn2   = (const float*)d_in[10];
    const float* Wc1   = (const float*)d_in[11];
    const float* bc1   = (const float*)d_in[12];
    const float* Wc2   = (const float*)d_in[13];

    float* out   = (float*)d_out;
    float* agg_h = out;                         // [NN,128] accum, then h_out
    float* agg_c = out + (size_t)NN * HD;       // [NN,3]  accum, then coord_out

    // workspace layout (16B alignment for bf16x8 loads)
    ushort_t* A    = (ushort_t*)d_ws;            // [NN,128] bf16
    ushort_t* B    = A + (size_t)NN * HD;        // [NN,128] bf16
    ushort_t* We2T = B + (size_t)NN * HD;        // [128,128] bf16
    ushort_t* Wc1T = We2T + HD * HD;             // [128,128] bf16
    int* deg    = (int*)(Wc1T + HD * HD);        // [NN]
    int* startv = deg + NN;                      // [NN]
    int* cursor = startv + NN;                   // [NN]
    int* perm   = cursor + NN;                   // [NE]
    const float* WeL = We1 + (size_t)2 * HD * HD;  // last row of We1

    hipMemsetAsync(d_out, 0, (size_t)out_size * sizeof(float), stream);
    hipMemsetAsync(deg, 0, (size_t)NN * sizeof(int), stream);

    k_prep<<<(2 * HD * HD + 255) / 256, 256, 0, stream>>>(We2, Wc1, We2T, Wc1T);
    k_hist<<<NE / 256, 256, 0, stream>>>(ei, deg);
    k_nodeAB<<<NN / 16, 256, 0, stream>>>(h, We1, be1, A, B);
    k_scan<<<1, 1024, 0, stream>>>(deg, startv, cursor);
    k_sortids<<<NE / 256, 256, 0, stream>>>(ei, cursor, perm);
    k_edge<<<NE / EB, 256, 0, stream>>>(ei, perm, coord, A, B, WeL, be2,
                                        We2T, Wc1T, bc1, Wc2, agg_h, agg_c);
    k_node<<<(NN + 255) / 256, 256, 0, stream>>>(h, Wn1, bn1, Wn2, bn2, coord,
                                                 deg, agg_h, agg_c);
}

// Round 5
// 1055.716 us; speedup vs baseline: 1.4423x; 1.2351x over previous
//
#include <hip/hip_runtime.h>

#define NN 100000
#define NE 1600000
#define HD 128
#define EPSV 1e-8f
#define EB 128      // edges per block in k_edge
#define LPAD 136    // padded LDS row length (bf16 elems): 272 B, 16B-aligned
#define CPAD 264    // padded row for 256-wide concat tile (528 B, 16B-aligned)

typedef unsigned short ushort_t;
typedef __attribute__((ext_vector_type(8))) short bf16x8;
typedef __attribute__((ext_vector_type(4))) float f32x4;

__device__ __forceinline__ float silu_f(float x) {
    // x * rcp(1+exp(-x)) : v_exp + v_rcp, ~1ulp — vs ~12-instr IEEE div
    return x * __builtin_amdgcn_rcpf(1.0f + __expf(-x));
}
__device__ __forceinline__ float b2f(unsigned short u) {
    union { unsigned int i; float f; } v; v.i = ((unsigned int)u) << 16; return v.f;
}
__device__ __forceinline__ unsigned short f2b(float f) {
    union { float f; unsigned int i; } v; v.f = f;
    unsigned int r = v.i + 0x7fff + ((v.i >> 16) & 1);
    return (unsigned short)(r >> 16);
}
// one instr converts two f32 -> packed bf16 (RNE)
__device__ __forceinline__ unsigned int cvt_pk_bf16(float lo, float hi) {
    unsigned int r;
    asm("v_cvt_pk_bf16_f32 %0, %1, %2" : "=v"(r) : "v"(lo), "v"(hi));
    return r;
}

// ---------------------------------------------------------------------------
// Kernel 0: build all bf16 transposed weight tables.
//   We2T[128][128], Wc1T[128][128], WabT[256][128], Wn1T[128][256], Wn2T[128][128]
// ---------------------------------------------------------------------------
extern "C" __global__ __launch_bounds__(256)
void k_prep(const float* __restrict__ We2, const float* __restrict__ Wc1,
            const float* __restrict__ We1, const float* __restrict__ Wn1,
            const float* __restrict__ Wn2,
            ushort_t* __restrict__ We2T, ushort_t* __restrict__ Wc1T,
            ushort_t* __restrict__ WabT, ushort_t* __restrict__ Wn1T,
            ushort_t* __restrict__ Wn2T)
{
    int id = blockIdx.x * 256 + threadIdx.x;
    if (id < 16384) {
        int n = id >> 7, k = id & 127;
        We2T[id] = f2b(We2[k * HD + n]);
    } else if (id < 32768) {
        int r = id - 16384; int n = r >> 7, k = r & 127;
        Wc1T[r] = f2b(Wc1[k * HD + n]);
    } else if (id < 65536) {
        int r = id - 32768; int j = r >> 7, k = r & 127;   // j in [0,256)
        float v = (j < 128) ? We1[k * HD + j] : We1[(size_t)(128 + k) * HD + (j - 128)];
        WabT[r] = f2b(v);
    } else if (id < 98304) {
        int r = id - 65536; int j = r >> 8, k = r & 255;   // [128][256]
        Wn1T[r] = f2b(Wn1[(size_t)k * HD + j]);
    } else if (id < 114688) {
        int r = id - 98304; int j = r >> 7, k = r & 127;
        Wn2T[r] = f2b(Wn2[k * HD + j]);
    }
}

// ---------------------------------------------------------------------------
// Counting sort of edges by row: histogram -> single-block scan -> scatter ids
// ---------------------------------------------------------------------------
extern "C" __global__ __launch_bounds__(256)
void k_hist(const int* __restrict__ ei, int* __restrict__ deg)
{
    int e = blockIdx.x * 256 + threadIdx.x;
    atomicAdd(&deg[ei[e]], 1);
}

extern "C" __global__ __launch_bounds__(1024)
void k_scan(const int* __restrict__ deg, int* __restrict__ cursor)
{
    __shared__ int wsum[16];
    __shared__ int carry_s;
    const int tid = threadIdx.x;
    const int lane = tid & 63, w = tid >> 6;
    if (tid == 0) carry_s = 0;
    __syncthreads();
    for (int base = 0; base < NN; base += 1024) {
        int i = base + tid;
        int v = (i < NN) ? deg[i] : 0;
        int s = v;
#pragma unroll
        for (int off = 1; off < 64; off <<= 1) {
            int t = __shfl_up(s, off, 64);
            if (lane >= off) s += t;
        }
        if (lane == 63) wsum[w] = s;
        __syncthreads();
        int carry = carry_s;
        if (w == 0) {
            int ws = (lane < 16) ? wsum[lane] : 0;
#pragma unroll
            for (int off = 1; off < 16; off <<= 1) {
                int t = __shfl_up(ws, off, 64);
                if (lane >= off) ws += t;
            }
            if (lane < 16) wsum[lane] = ws;
        }
        __syncthreads();
        int woff = (w == 0) ? 0 : wsum[w - 1];
        if (i < NN) cursor[i] = carry + woff + s - v;
        __syncthreads();
        if (tid == 0) carry_s = carry + wsum[15];
        __syncthreads();
    }
}

extern "C" __global__ __launch_bounds__(256)
void k_sortids(const int* __restrict__ ei, int* __restrict__ cursor,
               int* __restrict__ perm)
{
    int e = blockIdx.x * 256 + threadIdx.x;
    int slot = atomicAdd(&cursor[ei[e]], 1);
    perm[slot] = e;
}

// ---------------------------------------------------------------------------
// Kernel 1: MFMA  C[100k,256] = bf16(h) @ WabT  -> A (=+be1), B   (bf16 out)
// 64 nodes / block, 4 waves: wave w owns node rows [16w,16w+16).
// ---------------------------------------------------------------------------
extern "C" __global__ __launch_bounds__(256)
void k_ab(const float* __restrict__ h, const ushort_t* __restrict__ WabT,
          const float* __restrict__ be1,
          ushort_t* __restrict__ A, ushort_t* __restrict__ B)
{
    __shared__ ushort_t hs[64][LPAD] __attribute__((aligned(16)));
    const int tid = threadIdx.x;
    const int n0 = blockIdx.x * 64;
    {
        int r = tid >> 2, seg = tid & 3;
        int n = n0 + r; if (n >= NN) n = n0;   // clamp inside own block
        const float4* src = (const float4*)(h + (size_t)n * HD + seg * 32);
        uint2* dst = (uint2*)&hs[r][seg * 32];
#pragma unroll
        for (int i = 0; i < 8; i++) {
            float4 v = src[i];
            uint2 p; p.x = cvt_pk_bf16(v.x, v.y); p.y = cvt_pk_bf16(v.z, v.w);
            dst[i] = p;
        }
    }
    __syncthreads();
    const int wave = tid >> 6, lane = tid & 63;
    const int lr = lane & 15, lg = lane >> 4;
    f32x4 acc[16];
#pragma unroll
    for (int nt = 0; nt < 16; nt++) acc[nt] = (f32x4){0.f, 0.f, 0.f, 0.f};
#pragma unroll
    for (int ks = 0; ks < 4; ks++) {
        bf16x8 af = *(const bf16x8*)&hs[wave * 16 + lr][ks * 32 + lg * 8];
#pragma unroll
        for (int nt = 0; nt < 16; nt++) {
            bf16x8 bf = *(const bf16x8*)(WabT + (size_t)(nt * 16 + lr) * HD + ks * 32 + lg * 8);
            acc[nt] = __builtin_amdgcn_mfma_f32_16x16x32_bf16(af, bf, acc[nt], 0, 0, 0);
        }
    }
#pragma unroll
    for (int nt = 0; nt < 16; nt++) {
        float bias = (nt < 8) ? be1[nt * 16 + lr] : 0.f;
#pragma unroll
        for (int r = 0; r < 4; r++) {
            int n = n0 + wave * 16 + lg * 4 + r;
            if (n < NN) {
                ushort_t v = f2b(acc[nt][r] + bias);
                if (nt < 8) A[(size_t)n * HD + nt * 16 + lr] = v;
                else        B[(size_t)n * HD + (nt - 8) * 16 + lr] = v;
            }
        }
    }
}

// ---------------------------------------------------------------------------
// Kernel 2: MFMA edge kernel over SORTED edges (perm). Run-merged scatter.
// ---------------------------------------------------------------------------
extern "C" __global__ __launch_bounds__(256, 4)
void k_edge(const int* __restrict__ ei, const int* __restrict__ perm,
            const float* __restrict__ coord,
            const ushort_t* __restrict__ A, const ushort_t* __restrict__ B,
            const float* __restrict__ WeL, const float* __restrict__ be2,
            const ushort_t* __restrict__ We2T,
            const ushort_t* __restrict__ Wc1T,
            const float* __restrict__ bc1, const float* __restrict__ Wc2,
            float* __restrict__ agg_h, float* __restrict__ agg_c)
{
    __shared__ ushort_t m_lds[EB][LPAD] __attribute__((aligned(16)));
    __shared__ float cd_lds[EB][4];
    __shared__ int rows_s[EB];

    const int tid = threadIdx.x;
    const int e  = tid >> 1;       // edge slot 0..127 (sorted order)
    const int hf = tid & 1;        // feature half
    const int ge = perm[blockIdx.x * EB + e];
    const int row = ei[ge];
    const int col = ei[NE + ge];

    float c0 = coord[(size_t)row * 3 + 0] - coord[(size_t)col * 3 + 0];
    float c1 = coord[(size_t)row * 3 + 1] - coord[(size_t)col * 3 + 1];
    float c2 = coord[(size_t)row * 3 + 2] - coord[(size_t)col * 3 + 2];
    float radial = c0 * c0 + c1 * c1 + c2 * c2;
    if (hf == 0) {
        rows_s[e] = row;
        float inv = __builtin_amdgcn_rcpf(sqrtf(radial) + EPSV);
        cd_lds[e][0] = c0 * inv; cd_lds[e][1] = c1 * inv; cd_lds[e][2] = c2 * inv;
    }

    {
        const bf16x8* A8 = (const bf16x8*)(A + (size_t)row * HD + hf * 64);
        const bf16x8* B8 = (const bf16x8*)(B + (size_t)col * HD + hf * 64);
        const float4* WL4 = (const float4*)WeL + hf * 16;
#pragma unroll
        for (int i = 0; i < 8; i++) {
            bf16x8 av = A8[i], bv = B8[i];
            float4 w0 = WL4[2 * i], w1 = WL4[2 * i + 1];
            float v0 = silu_f(b2f((ushort_t)av[0]) + b2f((ushort_t)bv[0]) + radial * w0.x);
            float v1 = silu_f(b2f((ushort_t)av[1]) + b2f((ushort_t)bv[1]) + radial * w0.y);
            float v2 = silu_f(b2f((ushort_t)av[2]) + b2f((ushort_t)bv[2]) + radial * w0.z);
            float v3 = silu_f(b2f((ushort_t)av[3]) + b2f((ushort_t)bv[3]) + radial * w0.w);
            float v4 = silu_f(b2f((ushort_t)av[4]) + b2f((ushort_t)bv[4]) + radial * w1.x);
            float v5 = silu_f(b2f((ushort_t)av[5]) + b2f((ushort_t)bv[5]) + radial * w1.y);
            float v6 = silu_f(b2f((ushort_t)av[6]) + b2f((ushort_t)bv[6]) + radial * w1.z);
            float v7 = silu_f(b2f((ushort_t)av[7]) + b2f((ushort_t)bv[7]) + radial * w1.w);
            uint4 p;
            p.x = cvt_pk_bf16(v0, v1); p.y = cvt_pk_bf16(v2, v3);
            p.z = cvt_pk_bf16(v4, v5); p.w = cvt_pk_bf16(v6, v7);
            *(uint4*)&m_lds[e][hf * 64 + i * 8] = p;
        }
    }
    // no barrier: wave w wrote rows [32w,32w+32) and only reads those below

    const int wave = tid >> 6, lane = tid & 63;
    const int lr = lane & 15, lg = lane >> 4;

    // ---- GEMM1: m1 @ We2 ----
    f32x4 acc[2][8];
#pragma unroll
    for (int mt = 0; mt < 2; mt++)
#pragma unroll
        for (int nt = 0; nt < 8; nt++) acc[mt][nt] = (f32x4){0.f, 0.f, 0.f, 0.f};

#pragma unroll
    for (int ks = 0; ks < 4; ks++) {
        bf16x8 af0 = *(const bf16x8*)&m_lds[wave * 32 + lr][ks * 32 + lg * 8];
        bf16x8 af1 = *(const bf16x8*)&m_lds[wave * 32 + 16 + lr][ks * 32 + lg * 8];
#pragma unroll
        for (int nt = 0; nt < 8; nt++) {
            bf16x8 bf = *(const bf16x8*)(We2T + (size_t)(nt * 16 + lr) * HD + ks * 32 + lg * 8);
            acc[0][nt] = __builtin_amdgcn_mfma_f32_16x16x32_bf16(af0, bf, acc[0][nt], 0, 0, 0);
            acc[1][nt] = __builtin_amdgcn_mfma_f32_16x16x32_bf16(af1, bf, acc[1][nt], 0, 0, 0);
        }
    }

    // m = silu(acc + be2) -> back into m_lds (own wave's 32 rows only)
#pragma unroll
    for (int nt = 0; nt < 8; nt++) {
        float be2v = be2[nt * 16 + lr];
#pragma unroll
        for (int mt = 0; mt < 2; mt++)
#pragma unroll
            for (int r = 0; r < 4; r++) {
                int rrow = wave * 32 + mt * 16 + lg * 4 + r;
                m_lds[rrow][nt * 16 + lr] = f2b(silu_f(acc[mt][nt][r] + be2v));
            }
    }

    // ---- GEMM2: m @ Wc1 ----
#pragma unroll
    for (int mt = 0; mt < 2; mt++)
#pragma unroll
        for (int nt = 0; nt < 8; nt++) acc[mt][nt] = (f32x4){0.f, 0.f, 0.f, 0.f};

#pragma unroll
    for (int ks = 0; ks < 4; ks++) {
        bf16x8 af0 = *(const bf16x8*)&m_lds[wave * 32 + lr][ks * 32 + lg * 8];
        bf16x8 af1 = *(const bf16x8*)&m_lds[wave * 32 + 16 + lr][ks * 32 + lg * 8];
#pragma unroll
        for (int nt = 0; nt < 8; nt++) {
            bf16x8 bf = *(const bf16x8*)(Wc1T + (size_t)(nt * 16 + lr) * HD + ks * 32 + lg * 8);
            acc[0][nt] = __builtin_amdgcn_mfma_f32_16x16x32_bf16(af0, bf, acc[0][nt], 0, 0, 0);
            acc[1][nt] = __builtin_amdgcn_mfma_f32_16x16x32_bf16(af1, bf, acc[1][nt], 0, 0, 0);
        }
    }

    // phi = sum_j silu(u + bc1) * Wc2, reduced across the 16 col-lanes
    float ph[2][4];
#pragma unroll
    for (int mt = 0; mt < 2; mt++)
#pragma unroll
        for (int r = 0; r < 4; r++) ph[mt][r] = 0.f;
#pragma unroll
    for (int nt = 0; nt < 8; nt++) {
        float bc1v = bc1[nt * 16 + lr];
        float wc2v = Wc2[nt * 16 + lr];
#pragma unroll
        for (int mt = 0; mt < 2; mt++)
#pragma unroll
            for (int r = 0; r < 4; r++)
                ph[mt][r] += silu_f(acc[mt][nt][r] + bc1v) * wc2v;
    }
#pragma unroll
    for (int msk = 1; msk < 16; msk <<= 1)
#pragma unroll
        for (int mt = 0; mt < 2; mt++)
#pragma unroll
            for (int r = 0; r < 4; r++)
                ph[mt][r] += __shfl_xor(ph[mt][r], msk, 64);

    if (lr == 0) {
#pragma unroll
        for (int mt = 0; mt < 2; mt++)
#pragma unroll
            for (int r = 0; r < 4; r++) {
                int er = wave * 32 + mt * 16 + lg * 4 + r;
                float p = ph[mt][r];
                cd_lds[er][0] *= p; cd_lds[er][1] *= p; cd_lds[er][2] *= p;
            }
    }

    __syncthreads();   // the only barrier: walks read all waves' rows

    // ---- agg_h: run-merged scatter (rows sorted) ----
    {
        const int j = tid & 127, g = tid >> 7;
        const int es0 = g * 64, es1 = es0 + 64;
        float acc_r = 0.f;
        int cur = rows_s[es0];
        for (int es = es0; es < es1; es++) {
            int r = rows_s[es];
            if (r != cur) {
                atomicAdd(&agg_h[(size_t)cur * HD + j], acc_r);
                acc_r = 0.f; cur = r;
            }
            acc_r += b2f(m_lds[es][j]);
        }
        atomicAdd(&agg_h[(size_t)cur * HD + j], acc_r);
    }

    // ---- agg_c: same run-merge, wave 0 only ----
    if (wave == 0) {
        int c = lane >> 4;        // 0..3
        int sub = lane & 15;      // 0..15
        if (c < 3) {
            const int es0 = sub * 8, es1 = es0 + 8;
            float acc_r = 0.f;
            int cur = rows_s[es0];
            for (int es = es0; es < es1; es++) {
                int r = rows_s[es];
                if (r != cur) {
                    atomicAdd(&agg_c[(size_t)cur * 3 + c], acc_r);
                    acc_r = 0.f; cur = r;
                }
                acc_r += cd_lds[es][c];
            }
            atomicAdd(&agg_c[(size_t)cur * 3 + c], acc_r);
        }
    }
}

// ---------------------------------------------------------------------------
// Kernel 3: MFMA node MLP. 64 nodes / block, 4 waves.
//   u = silu([h|agg_h]@Wn1+bn1) ; hout = h + u@Wn2 + bn2 ; coord fixup.
// ---------------------------------------------------------------------------
extern "C" __global__ __launch_bounds__(256)
void k_node(const float* __restrict__ h, const ushort_t* __restrict__ Wn1T,
            const float* __restrict__ bn1, const ushort_t* __restrict__ Wn2T,
            const float* __restrict__ bn2, const float* __restrict__ coord,
            const int* __restrict__ deg,
            float* __restrict__ hout /* = agg_h in */,
            float* __restrict__ cout /* = agg_c in */)
{
    __shared__ ushort_t cs[64][CPAD] __attribute__((aligned(16)));
    __shared__ ushort_t us[64][LPAD] __attribute__((aligned(16)));
    const int tid = threadIdx.x;
    const int n0 = blockIdx.x * 64;
    {
        int r = tid >> 2, seg = tid & 3;
        int n = n0 + r; if (n >= NN) n = n0;   // clamp inside own block
        const float4* s0 = (const float4*)(h + (size_t)n * HD + seg * 32);
        const float4* s1 = (const float4*)(hout + (size_t)n * HD + seg * 32);
        uint2* d0 = (uint2*)&cs[r][seg * 32];
        uint2* d1 = (uint2*)&cs[r][128 + seg * 32];
#pragma unroll
        for (int i = 0; i < 8; i++) {
            float4 v = s0[i];
            uint2 p; p.x = cvt_pk_bf16(v.x, v.y); p.y = cvt_pk_bf16(v.z, v.w);
            d0[i] = p;
            float4 w = s1[i];
            uint2 q; q.x = cvt_pk_bf16(w.x, w.y); q.y = cvt_pk_bf16(w.z, w.w);
            d1[i] = q;
        }
    }
    __syncthreads();
    const int wave = tid >> 6, lane = tid & 63;
    const int lr = lane & 15, lg = lane >> 4;

    // ---- GEMM1: cat[64,256] @ Wn1 -> u ----
    f32x4 acc[8];
#pragma unroll
    for (int nt = 0; nt < 8; nt++) acc[nt] = (f32x4){0.f, 0.f, 0.f, 0.f};
#pragma unroll
    for (int ks = 0; ks < 8; ks++) {
        bf16x8 af = *(const bf16x8*)&cs[wave * 16 + lr][ks * 32 + lg * 8];
#pragma unroll
        for (int nt = 0; nt < 8; nt++) {
            bf16x8 bf = *(const bf16x8*)(Wn1T + (size_t)(nt * 16 + lr) * 256 + ks * 32 + lg * 8);
            acc[nt] = __builtin_amdgcn_mfma_f32_16x16x32_bf16(af, bf, acc[nt], 0, 0, 0);
        }
    }
#pragma unroll
    for (int nt = 0; nt < 8; nt++) {
        float bn1v = bn1[nt * 16 + lr];
#pragma unroll
        for (int r = 0; r < 4; r++)
            us[wave * 16 + lg * 4 + r][nt * 16 + lr] = f2b(silu_f(acc[nt][r] + bn1v));
    }
    // no barrier: wave-local rows

    // ---- GEMM2: u[64,128] @ Wn2 ----
#pragma unroll
    for (int nt = 0; nt < 8; nt++) acc[nt] = (f32x4){0.f, 0.f, 0.f, 0.f};
#pragma unroll
    for (int ks = 0; ks < 4; ks++) {
        bf16x8 af = *(const bf16x8*)&us[wave * 16 + lr][ks * 32 + lg * 8];
#pragma unroll
        for (int nt = 0; nt < 8; nt++) {
            bf16x8 bf = *(const bf16x8*)(Wn2T + (size_t)(nt * 16 + lr) * HD + ks * 32 + lg * 8);
            acc[nt] = __builtin_amdgcn_mfma_f32_16x16x32_bf16(af, bf, acc[nt], 0, 0, 0);
        }
    }
#pragma unroll
    for (int nt = 0; nt < 8; nt++) {
        float bn2v = bn2[nt * 16 + lr];
#pragma unroll
        for (int r = 0; r < 4; r++) {
            int n = n0 + wave * 16 + lg * 4 + r;
            if (n < NN) {
                size_t idx = (size_t)n * HD + nt * 16 + lr;
                hout[idx] = h[idx] + acc[nt][r] + bn2v;   // residual in fp32
            }
        }
    }

    if (tid < 64) {
        int n = n0 + tid;
        if (n < NN) {
            float invc = __builtin_amdgcn_rcpf(fmaxf((float)deg[n], 1.0f));
#pragma unroll
            for (int i = 0; i < 3; i++) {
                size_t idx = (size_t)n * 3 + i;
                cout[idx] = coord[idx] + cout[idx] * invc;
            }
        }
    }
}

// ---------------------------------------------------------------------------
extern "C" void kernel_launch(void* const* d_in, const int* in_sizes, int n_in,
                              void* d_out, int out_size, void* d_ws, size_t ws_size,
                              hipStream_t stream)
{
    const float* h     = (const float*)d_in[0];
    const int*   ei    = (const int*)d_in[1];
    const float* coord = (const float*)d_in[2];
    const float* We1   = (const float*)d_in[3];
    const float* be1   = (const float*)d_in[4];
    const float* We2   = (const float*)d_in[5];
    const float* be2   = (const float*)d_in[6];
    const float* Wn1   = (const float*)d_in[7];
    const float* bn1   = (const float*)d_in[8];
    const float* Wn2   = (const float*)d_in[9];
    const float* bn2   = (const float*)d_in[10];
    const float* Wc1   = (const float*)d_in[11];
    const float* bc1   = (const float*)d_in[12];
    const float* Wc2   = (const float*)d_in[13];

    float* out   = (float*)d_out;
    float* agg_h = out;                         // [NN,128] accum, then h_out
    float* agg_c = out + (size_t)NN * HD;       // [NN,3]  accum, then coord_out

    ushort_t* A    = (ushort_t*)d_ws;            // [NN,128] bf16
    ushort_t* B    = A + (size_t)NN * HD;        // [NN,128] bf16
    ushort_t* We2T = B + (size_t)NN * HD;        // [128,128]
    ushort_t* Wc1T = We2T + 16384;               // [128,128]
    ushort_t* WabT = Wc1T + 16384;               // [256,128]
    ushort_t* Wn1T = WabT + 32768;               // [128,256]
    ushort_t* Wn2T = Wn1T + 32768;               // [128,128]
    int* deg    = (int*)(Wn2T + 16384);          // [NN]
    int* cursor = deg + NN;                      // [NN]
    int* perm   = cursor + NN;                   // [NE]
    const float* WeL = We1 + (size_t)2 * HD * HD;  // last row of We1

    hipMemsetAsync(d_out, 0, (size_t)out_size * sizeof(float), stream);
    hipMemsetAsync(deg, 0, (size_t)NN * sizeof(int), stream);

    k_prep<<<448, 256, 0, stream>>>(We2, Wc1, We1, Wn1, Wn2,
                                    We2T, Wc1T, WabT, Wn1T, Wn2T);
    k_hist<<<NE / 256, 256, 0, stream>>>(ei, deg);
    k_ab<<<(NN + 63) / 64, 256, 0, stream>>>(h, WabT, be1, A, B);
    k_scan<<<1, 1024, 0, stream>>>(deg, cursor);
    k_sortids<<<NE / 256, 256, 0, stream>>>(ei, cursor, perm);
    k_edge<<<NE / EB, 256, 0, stream>>>(ei, perm, coord, A, B, WeL, be2,
                                        We2T, Wc1T, bc1, Wc2, agg_h, agg_c);
    k_node<<<(NN + 63) / 64, 256, 0, stream>>>(h, Wn1T, bn1, Wn2T, bn2, coord,
                                               deg, agg_h, agg_c);
}